// Round 8
// baseline (4713.464 us; speedup 1.0000x reference)
//
#include <hip/hip_runtime.h>

#define BB    128
#define SEQL  336
#define PREDN 24
#define IN    64
#define HH    256
#define GG    1024          // 4*H
#define KTOT  320           // IN + H
#define NBLK  128           // 2 dir x 8 q x 8 btile; 256 thr (4 waves)

typedef unsigned int   uint_t;
typedef unsigned short ush;
using s8v = __attribute__((ext_vector_type(8))) short;   // 8 bf16 (4 VGPRs)
using f4v = __attribute__((ext_vector_type(4))) float;   // MFMA acc

// ---- static device scratch (.bss; re-initialized by prep every call) ----
__device__ ush   g_webh[2 * 4 * 256 * KTOT];  // enc W bf16-hi [dir][gate][n][k]
__device__ ush   g_webl[2 * 4 * 256 * KTOT];  // enc W bf16-lo
__device__ ush   g_wdbh[2 * 4 * 256 * KTOT];  // dec W bf16-hi
__device__ ush   g_wdbl[2 * 4 * 256 * KTOT];  // dec W bf16-lo
__device__ float g_linwt[2 * HH * IN];        // [k2][o]
__device__ float g_bs_enc[2 * GG];
__device__ float g_bs_dec[2 * GG];
__device__ float g_linb[IN];
// h exchange: packed self-validating word (hi<<16)|(lo&0xFFFE)|tag, A-frag
// order, ping-pong by step parity. [(dir*8+btile)*2 + (g&1)][4096].
// cell (col,row): fi = ((col>>5)*64 + ((col&31)>>3)*16 + row)*8 + (col&7)
__device__ uint_t g_himg[16 * 2 * 4096];
// y feedback: once-written packed words (bit0=1 when valid). [t][btile][1024]
__device__ uint_t g_yimg[PREDN * 8 * 1024];
// final-h for heads: once-written packed words. [t][btile][dir][4096]
__device__ uint_t g_hfin[PREDN * 8 * 2 * 4096];

#define N_WT   (2 * 4 * 256 * KTOT)      // 655360
#define N_HIMG (16 * 2 * 4096)           // 131072
#define N_YIMG (PREDN * 8 * 1024)        // 196608
#define N_HFIN (PREDN * 8 * 2 * 4096)    // 1572864
#define N_PREP (2 * N_WT + 2 * HH * IN + 4 * GG + IN + N_HIMG + N_YIMG + N_HFIN)

__device__ __forceinline__ void bfsplit(float v, uint_t& hi, uint_t& lo) {
    uint_t u = __float_as_uint(v);
    uint_t h = (u + 0x7FFFu + ((u >> 16) & 1u)) >> 16;          // RTN-even bf16
    float  r = v - __uint_as_float(h << 16);
    uint_t u2 = __float_as_uint(r);
    uint_t l = (u2 + 0x7FFFu + ((u2 >> 16) & 1u)) >> 16;
    hi = h; lo = l;
}

// Weights -> bf16 hi/lo [dir][gate][n][k]; combine biases; init images.
__global__ void prep_kernel(const float* __restrict__ eWih,
                            const float* __restrict__ eWhh,
                            const float* __restrict__ ebih,
                            const float* __restrict__ ebhh,
                            const float* __restrict__ dWih,
                            const float* __restrict__ dWhh,
                            const float* __restrict__ dbih,
                            const float* __restrict__ dbhh,
                            const float* __restrict__ linW,
                            const float* __restrict__ linb)
{
    int idx = blockIdx.x * 256 + threadIdx.x;
    if (idx >= N_PREP) return;

    if (idx < N_WT) {                 // enc
        int d   = idx / (4 * 256 * KTOT);
        int sub = idx % (4 * 256 * KTOT);
        int g   = sub / (256 * KTOT);
        int n2  = (sub / KTOT) % 256;
        int k   = sub % KTOT;
        int j   = g * HH + n2;
        float v = (k < IN) ? eWih[(d * GG + j) * IN + k]
                           : eWhh[(d * GG + j) * HH + (k - IN)];
        uint_t hi, lo; bfsplit(v, hi, lo);
        g_webh[idx] = (ush)hi; g_webl[idx] = (ush)lo;
        return;
    }
    idx -= N_WT;
    if (idx < N_WT) {                 // dec
        int d   = idx / (4 * 256 * KTOT);
        int sub = idx % (4 * 256 * KTOT);
        int g   = sub / (256 * KTOT);
        int n2  = (sub / KTOT) % 256;
        int k   = sub % KTOT;
        int j   = g * HH + n2;
        float v = (k < IN) ? dWih[(d * GG + j) * IN + k]
                           : dWhh[(d * GG + j) * HH + (k - IN)];
        uint_t hi, lo; bfsplit(v, hi, lo);
        g_wdbh[idx] = (ush)hi; g_wdbl[idx] = (ush)lo;
        return;
    }
    idx -= N_WT;
    if (idx < 2 * HH * IN) {          // linWT[k2][o]
        int k = idx / IN, o = idx % IN;
        g_linwt[idx] = linW[o * (2 * HH) + k];
        return;
    }
    idx -= 2 * HH * IN;
    if (idx < 2 * GG) { g_bs_enc[idx] = ebih[idx] + ebhh[idx]; return; }
    idx -= 2 * GG;
    if (idx < 2 * GG) { g_bs_dec[idx] = dbih[idx] + dbhh[idx]; return; }
    idx -= 2 * GG;
    if (idx < IN) { g_linb[idx] = linb[idx]; return; }
    idx -= IN;
    // himg init: value 0, tag 1. Step 0 reads buffer 1 expecting tag 1
    // (valid zeros). Buffer 0 first read at step 1 expecting tag 0 ->
    // init tag 1 reads as stale until step 0's write lands.
    if (idx < N_HIMG) { g_himg[idx] = 0x00000001u; return; }
    idx -= N_HIMG;
    if (idx < N_YIMG) { g_yimg[idx] = 0u; return; }
    idx -= N_YIMG;
    if (idx < N_HFIN) { g_hfin[idx] = 0u; return; }
}

__device__ __forceinline__ float sigm(float v) { return 1.0f / (1.0f + expf(-v)); }

__device__ __forceinline__ uint_t agent_ldu(const uint_t* p) {
    return __hip_atomic_load(p, __ATOMIC_RELAXED, __HIP_MEMORY_SCOPE_AGENT);
}
__device__ __forceinline__ void agent_stu(uint_t* p, uint_t v) {
    __hip_atomic_store(p, v, __ATOMIC_RELAXED, __HIP_MEMORY_SCOPE_AGENT);
}

// PLAIN launch; 128 blocks <= 256 CUs co-reside trivially.
// blk = dir*64 + q*8 + btile. Group (dir,btile) = 8 q-blocks; block q owns
// n-cols [q*32, q*32+32); wave = gate over 2 col-tiles (B-frags 160 VGPR,
// register-resident -- R7-proven, VGPR_Count 156, no spill).
//
// h exchange is FLAG-FREE: producers publish packed self-validating words
// (data+tag in one 32-bit store, ping-pong by step parity); consumers spin
// on the tags of exactly the 16 words they stage (consumed-at-accept).
// ABA safety (group-local): a block writes step s+2 only after it consumed
// s+1, which requires every group peer to have written s+1, which requires
// each to have finished reading s -> nobody overwrites a buffer still being
// read; parity of s vs s+2 differs -> no false accept. Cross-dir data
// (head h, y feedback) uses ONCE-WRITTEN t-indexed images (monotonic tags,
// ABA-free regardless of inter-dir skew -- the round-3 lesson).
// Phase order per step (round-2 lesson): gather-to-regs (polls, x loads) ->
// barrier -> LDS sA writes -> barrier -> MFMA -> gbuf -> barrier -> act +
// single-store publish. One IC hop per step replaces R7's four.
__global__ __launch_bounds__(256, 1)
void lstm_main(const float* __restrict__ x, float* __restrict__ out)
{
    __shared__ __align__(16) ush  sAh[10 * 64 * 8];       // 10 KB  A hi (frag order)
    __shared__ __align__(16) ush  sAl[10 * 64 * 8];       // 10 KB  A lo
    __shared__ float gbuf[4][16][33];                     // 8.25 KB gate exchange
    __shared__ float umf[16][513];                        // 33 KB  head feat staging

    const int tid   = threadIdx.x;
    const int blk   = blockIdx.x;
    const int dir   = blk >> 6;
    const int q     = (blk >> 3) & 7;
    const int btile = blk & 7;
    const int b0    = btile * 16;
    const int wave  = tid >> 6;       // = gate index
    const int lane  = tid & 63;
    const int quad  = lane >> 4;
    const int n16   = lane & 15;

    s8v   rbh[2][10], rbl[2][10];     // this wave's B slice: gate=wave, 2 col-tiles
    float bw[2];
    auto load_w = [&](const ush* wh, const ush* wl, const float* bsrc) {
        #pragma unroll
        for (int t2 = 0; t2 < 2; ++t2) {
            int col = q * 32 + t2 * 16 + n16;
            #pragma unroll
            for (int kc = 0; kc < 10; ++kc) {
                int src = ((dir * 4 + wave) * 256 + col) * KTOT + kc * 32 + quad * 8;
                rbh[t2][kc] = *(const s8v*)(wh + src);
                rbl[t2][kc] = *(const s8v*)(wl + src);
            }
            bw[t2] = bsrc[dir * GG + wave * 256 + col];
        }
    };

    float cst[2] = {0.0f, 0.0f};
    int   g = 0;                      // global step counter (same in all blocks)

    // mode 0: encoder step tval; 1: decoder t=0 (x last step); 2: y sub-step.
    // fin_t >= 0: last sub-step of decoder iteration fin_t -> publish g_hfin.
    auto step = [&](int mode, int tval, int L, int fin_t) {
        // ===== phase 0: gather to registers (no LDS writes) =====
        float4 xv;
        uint_t w[16];
        if (mode <= 1) {
            int xb = tid >> 4, xj = tid & 15;
            int te = (mode == 0) ? (dir ? (SEQL - 1 - tval) : tval) : (SEQL - 1);
            xv = ((const float4*)(x + ((b0 + xb) * SEQL + te) * IN))[xj];
        } else {
            // y image is once-written: poll tags only, reload after accept.
            int e = dir ? (L - 1 - tval) : tval;
            const uint_t* yb_ = g_yimg + (e * 8 + btile) * 1024;
            for (;;) {
                uint_t andv = 0xFFFFFFFFu;
                #pragma unroll
                for (int jj = 0; jj < 4; ++jj) {
                    int i = tid + jj * 256;
                    int yb2 = i >> 6, k = i & 63;
                    int yi = ((k >> 5) * 64 + ((k & 31) >> 3) * 16 + yb2) * 8 + (k & 7);
                    andv &= agent_ldu(yb_ + yi);
                }
                if (andv & 1u) break;
                __builtin_amdgcn_s_sleep(1);
            }
        }
        {   // h poll: ping-pong image, consumed-at-accept (w[] IS the data)
            int    rb   = (g + 3) & 1;
            uint_t expt = (uint_t)(((g + 3) >> 1) & 1);
            const uint_t* img = g_himg + ((dir * 8 + btile) * 2 + rb) * 4096 + tid * 16;
            for (;;) {
                #pragma unroll
                for (int i = 0; i < 16; ++i) w[i] = agent_ldu(img + i);
                uint_t andv = w[0], orv = w[0];
                #pragma unroll
                for (int i = 1; i < 16; ++i) { andv &= w[i]; orv |= w[i]; }
                if (expt ? ((andv & 1u) == 1u) : ((orv & 1u) == 0u)) break;
                __builtin_amdgcn_s_sleep(1);
            }
        }
        __syncthreads();   // all waves done with prev step's MFMA reads of sA

        // ===== phase 1: write sA =====
        if (mode <= 1) {
            int xb = tid >> 4, xj = tid & 15;
            uint_t h0,l0,h1,l1,h2,l2,h3,l3;
            bfsplit(xv.x,h0,l0); bfsplit(xv.y,h1,l1); bfsplit(xv.z,h2,l2); bfsplit(xv.w,h3,l3);
            int k = 4 * xj;
            int base = (((k >> 5) * 64 + ((k & 31) >> 3) * 16 + xb) * 8) + (k & 7);
            *(uint_t*)&sAh[base]     = h0 | (h1 << 16);
            *(uint_t*)&sAh[base + 2] = h2 | (h3 << 16);
            *(uint_t*)&sAl[base]     = l0 | (l1 << 16);
            *(uint_t*)&sAl[base + 2] = l2 | (l3 << 16);
        } else {
            int e = dir ? (L - 1 - tval) : tval;
            const uint_t* yb_ = g_yimg + (e * 8 + btile) * 1024;
            #pragma unroll
            for (int jj = 0; jj < 4; ++jj) {
                int i = tid + jj * 256;
                int yb2 = i >> 6, k = i & 63;
                int yi = ((k >> 5) * 64 + ((k & 31) >> 3) * 16 + yb2) * 8 + (k & 7);
                uint_t wv = agent_ldu(yb_ + yi);     // once-written: reload safe
                sAh[yi] = (ush)(wv >> 16);
                sAl[yi] = (ush)(wv & 0xFFFEu);
            }
        }
        {   // h repack: 16 words -> 2 frag rows (k=64.. region starts at row 128)
            int r0 = (128 + 2 * tid) * 8;
            #pragma unroll
            for (int half = 0; half < 2; ++half) {
                uint_t hu[4], lu[4];
                #pragma unroll
                for (int q2 = 0; q2 < 4; ++q2) {
                    uint_t a = w[half * 8 + 2 * q2], bq = w[half * 8 + 2 * q2 + 1];
                    hu[q2] = (a >> 16) | (bq & 0xFFFF0000u);
                    lu[q2] = ((a & 0xFFFFu) | (bq << 16)) & 0xFFFEFFFEu;
                }
                *(uint4*)&sAh[r0 + half * 8] = make_uint4(hu[0], hu[1], hu[2], hu[3]);
                *(uint4*)&sAl[r0 + half * 8] = make_uint4(lu[0], lu[1], lu[2], lu[3]);
            }
        }
        __syncthreads();

        // ===== phase 2: MFMA (R7-proven): gate=wave, 2 tiles x 10 kc x 3 terms
        f4v a0 = {bw[0], bw[0], bw[0], bw[0]};
        f4v a1 = {bw[1], bw[1], bw[1], bw[1]};
        const s8v* pAh = (const s8v*)sAh;
        const s8v* pAl = (const s8v*)sAl;
        #pragma unroll
        for (int kc = 0; kc < 10; ++kc) {
            s8v ah = pAh[kc * 64 + lane];
            s8v al = pAl[kc * 64 + lane];
            a0 = __builtin_amdgcn_mfma_f32_16x16x32_bf16(ah, rbh[0][kc], a0, 0, 0, 0);
            a0 = __builtin_amdgcn_mfma_f32_16x16x32_bf16(ah, rbl[0][kc], a0, 0, 0, 0);
            a0 = __builtin_amdgcn_mfma_f32_16x16x32_bf16(al, rbh[0][kc], a0, 0, 0, 0);
            a1 = __builtin_amdgcn_mfma_f32_16x16x32_bf16(ah, rbh[1][kc], a1, 0, 0, 0);
            a1 = __builtin_amdgcn_mfma_f32_16x16x32_bf16(ah, rbl[1][kc], a1, 0, 0, 0);
            a1 = __builtin_amdgcn_mfma_f32_16x16x32_bf16(al, rbh[1][kc], a1, 0, 0, 0);
        }
        #pragma unroll
        for (int r2 = 0; r2 < 4; ++r2) {
            gbuf[wave][quad * 4 + r2][n16]      = a0[r2];
            gbuf[wave][quad * 4 + r2][16 + n16] = a1[r2];
        }
        __syncthreads();

        // ===== phase 3: activation + single-store tagged publish =====
        {
            uint_t* hw = g_himg + ((dir * 8 + btile) * 2 + (g & 1)) * 4096;
            uint_t  wt = (uint_t)((g >> 1) & 1);
            int row = tid >> 4, cp = (tid & 15) * 2;
            #pragma unroll
            for (int e2 = 0; e2 < 2; ++e2) {
                int col = cp + e2;
                float gi  = gbuf[0][row][col];
                float gf  = gbuf[1][row][col];
                float gg2 = gbuf[2][row][col];
                float go  = gbuf[3][row][col];
                cst[e2] = sigm(gf) * cst[e2] + sigm(gi) * tanhf(gg2);
                float hn = sigm(go) * tanhf(cst[e2]);
                int colG = q * 32 + col;
                uint_t hi, lo; bfsplit(hn, hi, lo);
                uint_t wd = (hi << 16) | (lo & 0xFFFEu);
                int fi = ((colG >> 5) * 64 + ((colG & 31) >> 3) * 16 + row) * 8 + (colG & 7);
                agent_stu(hw + fi, wd | wt);
                if (fin_t >= 0)
                    agent_stu(g_hfin + ((fin_t * 8 + btile) * 2 + dir) * 4096 + fi,
                              wd | 1u);
            }
        }
        ++g;
    };

    // ---- head (blk<8, i.e. dir0/q0): y = concat(hF,hB) @ linW^T + b ----
    auto head = [&](int t) {
        const uint_t* base0 = g_hfin + (t * 8 + btile) * 2 * 4096;
        // once-written: poll tags, reload after accept
        for (;;) {
            uint_t andv = 0xFFFFFFFFu;
            #pragma unroll
            for (int jj = 0; jj < 32; ++jj)
                andv &= agent_ldu(base0 + tid + jj * 256);
            if (andv & 1u) break;
            __builtin_amdgcn_s_sleep(1);
        }
        #pragma unroll
        for (int jj = 0; jj < 32; ++jj) {
            int gi = tid + jj * 256;
            uint_t wv = agent_ldu(base0 + gi);
            int d2 = gi >> 12, fi = gi & 4095;
            int j = fi & 7, r = fi >> 3;
            int row = r & 15, qd = (r >> 4) & 3, kc = r >> 6;
            umf[row][d2 * 256 + kc * 32 + qd * 8 + j] =
                __uint_as_float(wv & 0xFFFF0000u) +
                __uint_as_float((wv & 0xFFFEu) << 16);
        }
        __syncthreads();
        int row = tid >> 4, og = tid & 15;
        float acc[4];
        #pragma unroll
        for (int oi = 0; oi < 4; ++oi) acc[oi] = g_linb[og * 4 + oi];
        for (int k2 = 0; k2 < 512; ++k2) {
            float hv = umf[row][k2];
            #pragma unroll
            for (int oi = 0; oi < 4; ++oi)
                acc[oi] = fmaf(hv, g_linwt[k2 * IN + og * 4 + oi], acc[oi]);
        }
        uint_t* yw = g_yimg + (t * 8 + btile) * 1024;
        #pragma unroll
        for (int oi = 0; oi < 4; ++oi) {
            int o = og * 4 + oi;
            out[(b0 + row) * (PREDN * IN) + t * IN + o] = acc[oi];
            uint_t hi, lo; bfsplit(acc[oi], hi, lo);
            int yi = ((o >> 5) * 64 + ((o & 31) >> 3) * 16 + row) * 8 + (o & 7);
            agent_stu(yw + yi, (hi << 16) | (lo & 0xFFFEu) | 1u);
        }
        __syncthreads();   // umf settled before next step reuses LDS phases
    };

    // ---------------- encoder: 336 steps ----------------
    load_w(g_webh, g_webl, g_bs_enc);
    for (int t = 0; t < SEQL; ++t) step(0, t, 0, -1);

    load_w(g_wdbh, g_wdbl, g_bs_dec);   // registers only; no sync needed

    // ---------------- decoder: 24 iterations ----------------
    const int is_head = (blk < 8);
    for (int t = 0; t < PREDN; ++t) {
        int L = t ? t : 1;
        for (int s = 0; s < L; ++s)
            step((t == 0) ? 1 : 2, s, L, (s == L - 1) ? t : -1);
        if (is_head) head(t);
    }
}

extern "C" void kernel_launch(void* const* d_in, const int* in_sizes, int n_in,
                              void* d_out, int out_size, void* d_ws, size_t ws_size,
                              hipStream_t stream)
{
    (void)in_sizes; (void)n_in; (void)out_size; (void)d_ws; (void)ws_size;
    const float* x    = (const float*)d_in[0];
    const float* eWih = (const float*)d_in[1];
    const float* eWhh = (const float*)d_in[2];
    const float* ebih = (const float*)d_in[3];
    const float* ebhh = (const float*)d_in[4];
    const float* dWih = (const float*)d_in[5];
    const float* dWhh = (const float*)d_in[6];
    const float* dbih = (const float*)d_in[7];
    const float* dbhh = (const float*)d_in[8];
    const float* linW = (const float*)d_in[9];
    const float* linb = (const float*)d_in[10];
    float* out = (float*)d_out;

    int prep_blocks = (N_PREP + 255) / 256;
    hipLaunchKernelGGL(prep_kernel, dim3(prep_blocks), dim3(256), 0, stream,
                       eWih, eWhh, ebih, ebhh, dWih, dWhh, dbih, dbhh, linW, linb);

    // Plain launch: no grid-sync API used; 128 blocks <= 256 CUs co-reside.
    hipLaunchKernelGGL(lstm_main, dim3(NBLK), dim3(256), 0, stream, x, out);
}